// Round 9
// baseline (213.599 us; speedup 1.0000x reference)
//
#include <hip/hip_runtime.h>

// Problem constants (from reference)
constexpr int B   = 4;
constexpr int CF  = 3;    // feat channels
constexpr int CM  = 21;   // mask channels
constexpr int H   = 128;
constexpr int W   = 128;
constexpr int KS  = 7;
constexpr int PAD = 3;
constexpr int CENTER = (KS * KS) / 2;  // 24
constexpr int NNB = KS * KS - 1;       // 48 neighbors
constexpr int NUM_ITER = 10;

constexpr int TILE  = 16;
constexpr int TH    = TILE + 2 * PAD;  // 22
constexpr int TS    = 24;              // LDS row stride (even: b64-aligned pairs; 2tx steps cover all 32 banks at 4/bank)
constexpr int PLANE = TH * TS;         // 528
constexpr int HW    = H * W;

// ---------------------------------------------------------------------------
// Kernel 1: per-pixel 48-way softmax affinity from feats (validated).
// aff layout: aff[((b*48 + n)*H + h)*W + w]  (plane-major, coalesced in w)
// ---------------------------------------------------------------------------
__global__ __launch_bounds__(256) void aff_kernel(const float* __restrict__ feats,
                                                  float* __restrict__ aff) {
    __shared__ float tile[CF][TH][TS];
    const int tx = threadIdx.x, ty = threadIdx.y;
    const int bx = blockIdx.x * TILE, by = blockIdx.y * TILE;
    const int b  = blockIdx.z;
    const int tid = ty * TILE + tx;

    for (int c = 0; c < CF; ++c) {
        const float* src = feats + (size_t)(b * CF + c) * HW;
        for (int idx = tid; idx < TH * TH; idx += 256) {
            const int r  = idx / TH, cc = idx - r * TH;
            const int gh = min(max(by + r  - PAD, 0), H - 1);
            const int gw = min(max(bx + cc - PAD, 0), W - 1);
            tile[c][r][cc] = src[gh * W + gw];
        }
    }
    __syncthreads();

    float q[CF], inv[CF];
    #pragma unroll
    for (int c = 0; c < CF; ++c) {
        const float* tp = &tile[c][ty][tx];
        q[c] = tp[PAD * TS + PAD];
        float s = 0.f, s2 = 0.f;
        #pragma unroll
        for (int i = 0; i < KS; ++i)
            #pragma unroll
            for (int j = 0; j < KS; ++j) {
                if (i == PAD && j == PAD) continue;
                const float v = tp[i * TS + j];
                s += v; s2 += v * v;
            }
        const float mean = s * (1.0f / NNB);
        const float var  = fmaxf(s2 - (float)NNB * mean * mean, 0.f) * (1.0f / (NNB - 1));
        inv[c] = 1.0f / (1e-8f + 0.1f * sqrtf(var));
    }

    float a[NNB];
    float mx = -1e30f;
    #pragma unroll
    for (int i = 0; i < KS; ++i)
        #pragma unroll
        for (int j = 0; j < KS; ++j) {
            const int nn = i * KS + j;
            if (nn == CENTER) continue;
            const int n = (nn < CENTER) ? nn : nn - 1;
            float t = 0.f;
            #pragma unroll
            for (int c = 0; c < CF; ++c)
                t += fabsf(tile[c][ty + i][tx + j] - q[c]) * inv[c];
            a[n] = -t * (1.0f / CF);
            mx = fmaxf(mx, a[n]);
        }
    float ssum = 0.f;
    #pragma unroll
    for (int n = 0; n < NNB; ++n) { a[n] = __expf(a[n] - mx); ssum += a[n]; }
    const float rs = 1.0f / ssum;

    const int h = by + ty, w = bx + tx;
    #pragma unroll
    for (int n = 0; n < NNB; ++n)
        aff[(((size_t)b * NNB + n) * H + h) * W + w] = a[n] * rs;
}

// ---------------------------------------------------------------------------
// Kernel 2: one propagation iteration. Block (8,16,4)=512 thr, grid 256.
// Horizontal pixel pair per thread; 4 aligned ds_read_b64 per window row.
// __launch_bounds__(512,2): VGPR cap 256 -> a2[48] float2 CANNOT spill
// (round-8 fix). z-slice owns {6,5,5,5} channels. One __syncthreads.
// ---------------------------------------------------------------------------
__global__ __launch_bounds__(512, 2) void iter_kernel(const float* __restrict__ mi,
                                                      const float* __restrict__ aff,
                                                      float* __restrict__ mo) {
    __shared__ float mt[CM][TH][TS];     // 44.4 KB (mask halo tiles only)
    float* tf = &mt[0][0][0];

    const int tx = threadIdx.x;          // 0..7  (pixel-pair column)
    const int ty = threadIdx.y;          // 0..15
    const int tz = threadIdx.z;          // 0..3  (channel slice)
    const int bx = blockIdx.x * TILE, by = blockIdx.y * TILE;
    const int b  = blockIdx.z;
    const int tid = (tz * TILE + ty) * 8 + tx;
    const int h  = by + ty;
    const int w0 = bx + 2 * tx;

    const int c0  = (tz == 0) ? 0 : (1 + 5 * tz);   // {0,6,11,16}
    const int cnt = (tz == 0) ? 6 : 5;

    // ---- aff -> 48 float2 registers (8B loads, L2/L3-resident, read once)
    float2 a2[NNB];
    {
        const float* ab = aff + (size_t)b * NNB * HW + h * W + w0;
        #pragma unroll
        for (int n = 0; n < NNB; ++n)
            a2[n] = *(const float2*)(ab + (size_t)n * HW);
    }

    // ---- stage all 21 channel halo tiles: exactly 1 slot/thread (484<512)
    if (tid < TH * TH) {
        const int r  = tid / TH, q = tid - r * TH;
        const int gh = min(max(by + r - PAD, 0), H - 1);
        const int gw = min(max(bx + q - PAD, 0), W - 1);
        const int go = gh * W + gw, lo = r * TS + q;
        const float* src = mi + (size_t)b * CM * HW;
        #pragma unroll
        for (int c = 0; c < CM; ++c)
            tf[c * PLANE + lo] = src[c * HW + go];
    }
    __syncthreads();

    // ---- per channel: 7 rows x 4 ds_read_b64, 96 FMAs for the pixel pair
    float* dp = mo + (size_t)b * CM * HW + h * W + w0;
    for (int k = 0; k < cnt; ++k) {       // cnt is wave-uniform (tz/wave)
        const int c = c0 + k;
        const float* tp = tf + c * PLANE + ty * TS + 2 * tx;
        float s0 = 0.f, s1 = 0.f;
        #pragma unroll
        for (int i = 0; i < KS; ++i) {
            const float2 r0 = *(const float2*)(tp + i * TS);
            const float2 r1 = *(const float2*)(tp + i * TS + 2);
            const float2 r2 = *(const float2*)(tp + i * TS + 4);
            const float2 r3 = *(const float2*)(tp + i * TS + 6);
            const float rr[8] = { r0.x, r0.y, r1.x, r1.y, r2.x, r2.y, r3.x, r3.y };
            #pragma unroll
            for (int j = 0; j < KS; ++j) {
                const int nn = i * KS + j;
                if (nn == CENTER) continue;          // center skipped for BOTH pixels
                const int n = (nn < CENTER) ? nn : nn - 1;
                s0 += a2[n].x * rr[j];               // pixel p   : window col j
                s1 += a2[n].y * rr[j + 1];           // pixel p+1 : window col j+1
            }
        }
        *(float2*)(dp + (size_t)c * HW) = make_float2(s0, s1);
    }
}

// ---------------------------------------------------------------------------
extern "C" void kernel_launch(void* const* d_in, const int* in_sizes, int n_in,
                              void* d_out, int out_size, void* d_ws, size_t ws_size,
                              hipStream_t stream) {
    const float* feats = (const float*)d_in[0];
    const float* mask  = (const float*)d_in[1];
    float* out = (float*)d_out;

    float* aff  = (float*)d_ws;                               // 12.58 MB
    float* buf0 = aff  + (size_t)B * NNB * HW;                // 5.5 MB
    float* buf1 = buf0 + (size_t)B * CM  * HW;                // 5.5 MB

    dim3 grid(W / TILE, H / TILE, B);
    aff_kernel<<<grid, dim3(TILE, TILE), 0, stream>>>(feats, aff);

    const float* srcp = mask;
    for (int t = 1; t <= NUM_ITER; ++t) {
        float* dst = (t == NUM_ITER) ? out : ((t & 1) ? buf0 : buf1);
        iter_kernel<<<grid, dim3(8, TILE, 4), 0, stream>>>(srcp, aff, dst);
        srcp = dst;
    }
}

// Round 10
// 192.494 us; speedup vs baseline: 1.1096x; 1.1096x over previous
//
#include <hip/hip_runtime.h>

// Problem constants (from reference)
constexpr int B   = 4;
constexpr int CF  = 3;    // feat channels
constexpr int CM  = 21;   // mask channels
constexpr int H   = 128;
constexpr int W   = 128;
constexpr int KS  = 7;
constexpr int PAD = 3;
constexpr int CENTER = (KS * KS) / 2;  // 24
constexpr int NNB = KS * KS - 1;       // 48 neighbors
constexpr int NUM_ITER = 10;

constexpr int TILE  = 16;
constexpr int TH    = TILE + 2 * PAD;  // 22
constexpr int TS    = 24;              // LDS row stride: ty*24 % 32 in {0,24,16,8} -> exact 2-way aliasing (free)
constexpr int PLANE = TH * TS;         // 528
constexpr int HW    = H * W;
constexpr int NG    = 4;               // channel groups {6,5,5,5}
constexpr int CMAX  = 6;

// ---------------------------------------------------------------------------
// Kernel 1: per-pixel 48-way softmax affinity from feats (validated).
// aff layout: aff[((b*48 + n)*H + h)*W + w]  (plane-major, coalesced in w)
// ---------------------------------------------------------------------------
__global__ __launch_bounds__(256) void aff_kernel(const float* __restrict__ feats,
                                                  float* __restrict__ aff) {
    __shared__ float tile[CF][TH][TS];
    const int tx = threadIdx.x, ty = threadIdx.y;
    const int bx = blockIdx.x * TILE, by = blockIdx.y * TILE;
    const int b  = blockIdx.z;
    const int tid = ty * TILE + tx;

    for (int c = 0; c < CF; ++c) {
        const float* src = feats + (size_t)(b * CF + c) * HW;
        for (int idx = tid; idx < TH * TH; idx += 256) {
            const int r  = idx / TH, cc = idx - r * TH;
            const int gh = min(max(by + r  - PAD, 0), H - 1);
            const int gw = min(max(bx + cc - PAD, 0), W - 1);
            tile[c][r][cc] = src[gh * W + gw];
        }
    }
    __syncthreads();

    float q[CF], inv[CF];
    #pragma unroll
    for (int c = 0; c < CF; ++c) {
        const float* tp = &tile[c][ty][tx];
        q[c] = tp[PAD * TS + PAD];
        float s = 0.f, s2 = 0.f;
        #pragma unroll
        for (int i = 0; i < KS; ++i)
            #pragma unroll
            for (int j = 0; j < KS; ++j) {
                if (i == PAD && j == PAD) continue;
                const float v = tp[i * TS + j];
                s += v; s2 += v * v;
            }
        const float mean = s * (1.0f / NNB);
        const float var  = fmaxf(s2 - (float)NNB * mean * mean, 0.f) * (1.0f / (NNB - 1));
        inv[c] = 1.0f / (1e-8f + 0.1f * sqrtf(var));
    }

    float a[NNB];
    float mx = -1e30f;
    #pragma unroll
    for (int i = 0; i < KS; ++i)
        #pragma unroll
        for (int j = 0; j < KS; ++j) {
            const int nn = i * KS + j;
            if (nn == CENTER) continue;
            const int n = (nn < CENTER) ? nn : nn - 1;
            float t = 0.f;
            #pragma unroll
            for (int c = 0; c < CF; ++c)
                t += fabsf(tile[c][ty + i][tx + j] - q[c]) * inv[c];
            a[n] = -t * (1.0f / CF);
            mx = fmaxf(mx, a[n]);
        }
    float ssum = 0.f;
    #pragma unroll
    for (int n = 0; n < NNB; ++n) { a[n] = __expf(a[n] - mx); ssum += a[n]; }
    const float rs = 1.0f / ssum;

    const int h = by + ty, w = bx + tx;
    #pragma unroll
    for (int n = 0; n < NNB; ++n)
        aff[(((size_t)b * NNB + n) * H + h) * W + w] = a[n] * rs;
}

// ---------------------------------------------------------------------------
// Kernel 2: one propagation iteration.
// 256-thr blocks (4-wave sync domain), channel groups {6,5,5,5} ->
// grid (8,8,4*4) = 1024 blocks = 4 independent blocks/CU = 16 waves/CU.
// LDS 12.7 KB/block; one __syncthreads; aff in 48 f32 registers; b32 taps.
// ---------------------------------------------------------------------------
__global__ __launch_bounds__(256, 4) void iter_kernel(const float* __restrict__ mi,
                                                      const float* __restrict__ aff,
                                                      float* __restrict__ mo) {
    __shared__ float mt[CMAX][TH][TS];   // up to 6 channel halo planes (12.7 KB)
    float* tf = &mt[0][0][0];

    const int tx = threadIdx.x, ty = threadIdx.y;
    const int bx = blockIdx.x * TILE, by = blockIdx.y * TILE;
    const int zz = blockIdx.z;
    const int b  = zz >> 2;
    const int g  = zz & 3;
    const int c0  = (g == 0) ? 0 : (1 + 5 * g);    // {0,6,11,16}
    const int cnt = (g == 0) ? 6 : 5;
    const int tid = ty * TILE + tx;
    const int h = by + ty, w = bx + tx;

    // ---- aff -> 48 f32 registers (coalesced plane loads, L2/L3-resident)
    float a[NNB];
    {
        const float* ab = aff + (size_t)b * NNB * HW + h * W + w;
        #pragma unroll
        for (int n = 0; n < NNB; ++n)
            a[n] = ab[(size_t)n * HW];
    }

    // ---- stage this group's channel halo tiles (2 slots/thread, cnt planes)
    {
        const float* src = mi + (size_t)(b * CM + c0) * HW;
        #pragma unroll
        for (int k = 0; k < 2; ++k) {
            const int slot = tid + k * 256;
            if (slot < TH * TH) {
                const int r  = slot / TH, q = slot - r * TH;
                const int gh = min(max(by + r - PAD, 0), H - 1);
                const int gw = min(max(bx + q - PAD, 0), W - 1);
                const int go = gh * W + gw, lo = r * TS + q;
                for (int c = 0; c < cnt; ++c)
                    tf[c * PLANE + lo] = src[c * HW + go];
            }
        }
    }
    __syncthreads();

    // ---- cnt channels x 48 taps per thread (proven R1 tap loop)
    float* dp = mo + (size_t)(b * CM + c0) * HW + h * W + w;
    for (int k = 0; k < cnt; ++k) {
        const float* tp = tf + k * PLANE + ty * TS + tx;
        float s = 0.f;
        #pragma unroll
        for (int i = 0; i < KS; ++i)
            #pragma unroll
            for (int j = 0; j < KS; ++j) {
                const int nn = i * KS + j;
                if (nn == CENTER) continue;
                const int n = (nn < CENTER) ? nn : nn - 1;
                s += a[n] * tp[i * TS + j];
            }
        dp[(size_t)k * HW] = s;
    }
}

// ---------------------------------------------------------------------------
extern "C" void kernel_launch(void* const* d_in, const int* in_sizes, int n_in,
                              void* d_out, int out_size, void* d_ws, size_t ws_size,
                              hipStream_t stream) {
    const float* feats = (const float*)d_in[0];
    const float* mask  = (const float*)d_in[1];
    float* out = (float*)d_out;

    float* aff  = (float*)d_ws;                               // 12.58 MB
    float* buf0 = aff  + (size_t)B * NNB * HW;                // 5.5 MB
    float* buf1 = buf0 + (size_t)B * CM  * HW;                // 5.5 MB

    aff_kernel<<<dim3(W / TILE, H / TILE, B), dim3(TILE, TILE), 0, stream>>>(feats, aff);

    dim3 grid_it(W / TILE, H / TILE, B * NG);
    const float* srcp = mask;
    for (int t = 1; t <= NUM_ITER; ++t) {
        float* dst = (t == NUM_ITER) ? out : ((t & 1) ? buf0 : buf1);
        iter_kernel<<<grid_it, dim3(TILE, TILE), 0, stream>>>(srcp, aff, dst);
        srcp = dst;
    }
}

// Round 11
// 162.961 us; speedup vs baseline: 1.3107x; 1.1812x over previous
//
#include <hip/hip_runtime.h>

// Problem constants (from reference)
constexpr int B   = 4;
constexpr int CF  = 3;    // feat channels
constexpr int CM  = 21;   // mask channels
constexpr int H   = 128;
constexpr int W   = 128;
constexpr int KS  = 7;
constexpr int PAD = 3;
constexpr int CENTER = (KS * KS) / 2;  // 24
constexpr int NNB = KS * KS - 1;       // 48 neighbors
constexpr int NUM_ITER = 10;

constexpr int TILE = 16;
constexpr int TH   = TILE + 2 * PAD;   // 22 (aff-kernel halo tile)
constexpr int TS   = 24;
constexpr int HW   = H * W;

// fuse-2 geometry
constexpr int IN   = TILE + 4 * PAD;   // 28 input halo tile (2 iterations deep)
constexpr int INS  = 30;               // input LDS row stride
constexpr int MD   = 22;               // intermediate (iter t) region
constexpr int MDS  = 24;               // intermediate LDS row stride
constexpr int CPB  = 7;                // channels per block (3 groups)
constexpr int RING = MD * MD - TILE * TILE;  // 228 halo-ring pixels

// ---------------------------------------------------------------------------
// Kernel 1: per-pixel 48-way softmax affinity from feats (validated R4-R10).
// aff layout: aff[((b*48 + n)*H + h)*W + w]
// ---------------------------------------------------------------------------
__global__ __launch_bounds__(256) void aff_kernel(const float* __restrict__ feats,
                                                  float* __restrict__ aff) {
    __shared__ float tile[CF][TH][TS];
    const int tx = threadIdx.x, ty = threadIdx.y;
    const int bx = blockIdx.x * TILE, by = blockIdx.y * TILE;
    const int b  = blockIdx.z;
    const int tid = ty * TILE + tx;

    for (int c = 0; c < CF; ++c) {
        const float* src = feats + (size_t)(b * CF + c) * HW;
        for (int idx = tid; idx < TH * TH; idx += 256) {
            const int r  = idx / TH, cc = idx - r * TH;
            const int gh = min(max(by + r  - PAD, 0), H - 1);
            const int gw = min(max(bx + cc - PAD, 0), W - 1);
            tile[c][r][cc] = src[gh * W + gw];
        }
    }
    __syncthreads();

    float q[CF], inv[CF];
    #pragma unroll
    for (int c = 0; c < CF; ++c) {
        const float* tp = &tile[c][ty][tx];
        q[c] = tp[PAD * TS + PAD];
        float s = 0.f, s2 = 0.f;
        #pragma unroll
        for (int i = 0; i < KS; ++i)
            #pragma unroll
            for (int j = 0; j < KS; ++j) {
                if (i == PAD && j == PAD) continue;
                const float v = tp[i * TS + j];
                s += v; s2 += v * v;
            }
        const float mean = s * (1.0f / NNB);
        const float var  = fmaxf(s2 - (float)NNB * mean * mean, 0.f) * (1.0f / (NNB - 1));
        inv[c] = 1.0f / (1e-8f + 0.1f * sqrtf(var));
    }

    float a[NNB];
    float mx = -1e30f;
    #pragma unroll
    for (int i = 0; i < KS; ++i)
        #pragma unroll
        for (int j = 0; j < KS; ++j) {
            const int nn = i * KS + j;
            if (nn == CENTER) continue;
            const int n = (nn < CENTER) ? nn : nn - 1;
            float t = 0.f;
            #pragma unroll
            for (int c = 0; c < CF; ++c)
                t += fabsf(tile[c][ty + i][tx + j] - q[c]) * inv[c];
            a[n] = -t * (1.0f / CF);
            mx = fmaxf(mx, a[n]);
        }
    float ssum = 0.f;
    #pragma unroll
    for (int n = 0; n < NNB; ++n) { a[n] = __expf(a[n] - mx); ssum += a[n]; }
    const float rs = 1.0f / ssum;

    const int h = by + ty, w = bx + tx;
    #pragma unroll
    for (int n = 0; n < NNB; ++n)
        aff[(((size_t)b * NNB + n) * H + h) * W + w] = a[n] * rs;
}

// ---------------------------------------------------------------------------
// Kernel 2: TWO fused propagation iterations.
// Stage 28x28x7ch input -> pass1: iter t on 22x22 into LDS (own px uses aff
// regs; 228 ring px load their own aff) -> pass2: iter t+1 on 16x16 -> store.
// Intermediate never touches global. 768 blocks, 256 thr, 3 blocks/CU.
// ---------------------------------------------------------------------------
__global__ __launch_bounds__(256, 3) void fuse2_kernel(const float* __restrict__ mi,
                                                       const float* __restrict__ aff,
                                                       float* __restrict__ mo) {
    __shared__ float in_t[CPB][IN][INS];   // 23.5 KB
    __shared__ float mid_t[CPB][MD][MDS];  // 14.8 KB

    const int tx = threadIdx.x, ty = threadIdx.y;
    const int bx = blockIdx.x * TILE, by = blockIdx.y * TILE;
    const int zz = blockIdx.z;
    const int b  = zz / 3, g = zz % 3;
    const int c0 = g * CPB;
    const int tid = ty * TILE + tx;
    const int h = by + ty, w = bx + tx;

    const float* ab = aff + (size_t)b * NNB * HW;

    // ---- own-pixel aff -> 48 registers (used in BOTH passes)
    float a[NNB];
    #pragma unroll
    for (int n = 0; n < NNB; ++n)
        a[n] = ab[(size_t)n * HW + h * W + w];

    // ---- stage input halo tile 28x28 x 7ch (edge-clamped)
    {
        const float* src = mi + (size_t)(b * CM + c0) * HW;
        for (int s = tid; s < IN * IN; s += 256) {
            const int r  = s / IN, q = s - r * IN;
            const int gh = min(max(by - 2 * PAD + r, 0), H - 1);
            const int gw = min(max(bx - 2 * PAD + q, 0), W - 1);
            const int go = gh * W + gw;
            #pragma unroll
            for (int c = 0; c < CPB; ++c)
                in_t[c][r][q] = src[c * HW + go];
        }
    }
    __syncthreads();

    // ---- pass 1a: iteration t at OWN pixel (aff regs), write to mid LDS
    #pragma unroll
    for (int c = 0; c < CPB; ++c) {
        const float* tp = &in_t[c][ty + PAD][tx + PAD];  // window origin rows ty+3..ty+9
        float s = 0.f;
        #pragma unroll
        for (int i = 0; i < KS; ++i)
            #pragma unroll
            for (int j = 0; j < KS; ++j) {
                const int nn = i * KS + j;
                if (nn == CENTER) continue;
                const int n = (nn < CENTER) ? nn : nn - 1;
                s += a[n] * tp[i * INS + j];
            }
        mid_t[c][ty + PAD][tx + PAD] = s;
    }

    // ---- pass 1b: iteration t at the 228 halo-ring pixels
    if (tid < RING) {
        int r, q;
        if (tid < 3 * MD)            { r = tid / MD;             q = tid - r * MD; }
        else if (tid < 6 * MD)       { const int s2 = tid - 3 * MD;
                                       r = (MD - PAD) + s2 / MD; q = s2 % MD; }
        else                         { const int s2 = tid - 6 * MD;
                                       r = PAD + s2 / 6;
                                       const int qq = s2 % 6;
                                       q = (qq < 3) ? qq : (MD - PAD + qq - 3); }
        const int gh = min(max(by - PAD + r, 0), H - 1);
        const int gw = min(max(bx - PAD + q, 0), W - 1);

        float ar[NNB];
        #pragma unroll
        for (int n = 0; n < NNB; ++n)
            ar[n] = ab[(size_t)n * HW + gh * W + gw];

        const int ri0 = gh - by + 2 * PAD;   // window top-left in input tile
        const int qi0 = gw - bx + 2 * PAD;
        #pragma unroll
        for (int c = 0; c < CPB; ++c) {
            const float* tp = &in_t[c][ri0 - PAD][qi0 - PAD];
            float s = 0.f;
            #pragma unroll
            for (int i = 0; i < KS; ++i)
                #pragma unroll
                for (int j = 0; j < KS; ++j) {
                    const int nn = i * KS + j;
                    if (nn == CENTER) continue;
                    const int n = (nn < CENTER) ? nn : nn - 1;
                    s += ar[n] * tp[i * INS + j];
                }
            mid_t[c][r][q] = s;
        }
    }
    __syncthreads();

    // ---- pass 2: iteration t+1 at own pixel from mid LDS, store
    float* dp = mo + (size_t)(b * CM + c0) * HW + h * W + w;
    #pragma unroll
    for (int c = 0; c < CPB; ++c) {
        const float* tp = &mid_t[c][ty][tx];   // own px at (ty+3,tx+3); window rows ty..ty+6
        float s = 0.f;
        #pragma unroll
        for (int i = 0; i < KS; ++i)
            #pragma unroll
            for (int j = 0; j < KS; ++j) {
                const int nn = i * KS + j;
                if (nn == CENTER) continue;
                const int n = (nn < CENTER) ? nn : nn - 1;
                s += a[n] * tp[i * MDS + j];
            }
        dp[(size_t)c * HW] = s;
    }
}

// ---------------------------------------------------------------------------
extern "C" void kernel_launch(void* const* d_in, const int* in_sizes, int n_in,
                              void* d_out, int out_size, void* d_ws, size_t ws_size,
                              hipStream_t stream) {
    const float* feats = (const float*)d_in[0];
    const float* mask  = (const float*)d_in[1];
    float* out = (float*)d_out;

    float* aff  = (float*)d_ws;                               // 12.58 MB
    float* buf0 = aff  + (size_t)B * NNB * HW;                // 5.5 MB
    float* buf1 = buf0 + (size_t)B * CM  * HW;                // 5.5 MB

    aff_kernel<<<dim3(W / TILE, H / TILE, B), dim3(TILE, TILE), 0, stream>>>(feats, aff);

    // 5 fused kernels = 10 iterations; last lands in d_out
    dim3 grid(W / TILE, H / TILE, B * 3);
    dim3 blk(TILE, TILE);
    fuse2_kernel<<<grid, blk, 0, stream>>>(mask, aff, buf0);
    fuse2_kernel<<<grid, blk, 0, stream>>>(buf0, aff, buf1);
    fuse2_kernel<<<grid, blk, 0, stream>>>(buf1, aff, buf0);
    fuse2_kernel<<<grid, blk, 0, stream>>>(buf0, aff, buf1);
    fuse2_kernel<<<grid, blk, 0, stream>>>(buf1, aff, out);
}